// Round 11
// baseline (208.036 us; speedup 1.0000x reference)
//
#include <hip/hip_runtime.h>
#include <math.h>

#define BB 4
#define TT 4096
#define EE 1024
#define HH 64

typedef __attribute__((ext_vector_type(8))) short bf16x8;    // 8 bf16 = 4 VGPRs
typedef __attribute__((ext_vector_type(4))) float f32x4;
typedef __attribute__((ext_vector_type(16))) float f32x16;

#define MFMA16(a, b, c) __builtin_amdgcn_mfma_f32_16x16x32_bf16(a, b, c, 0, 0, 0)
#define MFMA32(a, b, c) __builtin_amdgcn_mfma_f32_32x32x16_bf16(a, b, c, 0, 0, 0)

__device__ __forceinline__ unsigned short f2bf_rne(float f) {
    unsigned u = __float_as_uint(f);
    unsigned r = u + 0x7fffu + ((u >> 16) & 1u);   // round-to-nearest-even
    return (unsigned short)(r >> 16);
}
__device__ __forceinline__ float bf2f(unsigned short h) {
    return __uint_as_float(((unsigned)h) << 16);
}

// async 16B global->LDS DMA; LDS dest = base + lane*16 (wave-uniform base)
__device__ __forceinline__ void async_copy16(const void* g, void* l) {
    __builtin_amdgcn_global_load_lds(
        (const __attribute__((address_space(1))) void*)g,
        (__attribute__((address_space(3))) void*)l, 16, 0, 0);
}
// wait until <= N vector-memory ops outstanding (lgkm/exp untouched)
template<int N>
__device__ __forceinline__ void wait_vm() {
    __builtin_amdgcn_s_waitcnt(0x0f70 | (N & 15) | ((N >> 4) << 14));
}

// ---------------------------------------------------------------------------
// Kernel 0: W prep via LDS transpose.  wt_hi/lo[h192][e] = split-bf16 of
// W{q|k|v}[e][h].  48 blocks.  (unchanged)
// ---------------------------------------------------------------------------
__global__ __launch_bounds__(256) void wprep_kernel(
    const float* __restrict__ Wq, const float* __restrict__ Wk,
    const float* __restrict__ Wv,
    unsigned short* __restrict__ wt_hi, unsigned short* __restrict__ wt_lo)
{
    __shared__ float ts[64][65];
    const int which = blockIdx.x >> 4;
    const int e0 = (blockIdx.x & 15) * 64;
    const float* W = (which == 0) ? Wq : ((which == 1) ? Wk : Wv);
    const int t = threadIdx.x;
    const int h = t & 63;
    #pragma unroll
    for (int p = 0; p < 16; p++) {
        const int er = (t >> 6) + p * 4;
        ts[er][h] = W[(size_t)(e0 + er) * 64 + h];
    }
    __syncthreads();
    const int ew = t & 63;
    #pragma unroll
    for (int p = 0; p < 16; p++) {
        const int hh = (t >> 6) + p * 4;
        const float f = ts[ew][hh];
        const unsigned short hb = f2bf_rne(f);
        const unsigned short lb = f2bf_rne(f - bf2f(hb));
        const size_t o = (size_t)(which * 64 + hh) * 1024 + e0 + ew;
        wt_hi[o] = hb;
        wt_lo[o] = lb;
    }
}

// ---------------------------------------------------------------------------
// Kernel 1: QKV projection, 2 blocks/CU (R10 post-mortem: single-block
// lockstep was the ceiling — all 8 waves gated on one barrier+waitcnt chain
// with nothing to fill the stall).  Block = 384 thr = 6 waves, 32 tokens;
// wave w owns ONE 32x32 output tile (rows [w*32, w*32+32) of 192 h) — no
// reduction merge at all.  Stage [192h][32e] hi+lo = 24 KB, double-buffered
// (49152 B LDS -> 512 blocks = 2/CU).  One barrier + one wait_vm(0) per
// step; DMA(s+1) issued right after the top-of-s barrier (overwrite-safe:
// barrier proves step s-1 reads done).  x prefetched one step in regs.
// Rows are 128 B with 16B slots XOR-swizzled by row&7 (conflict-free b128).
// ---------------------------------------------------------------------------
__global__ __launch_bounds__(384) void proj_kernel(
    const float* __restrict__ x,
    const unsigned short* __restrict__ wt_hi, const unsigned short* __restrict__ wt_lo,
    unsigned short* __restrict__ qhi, unsigned short* __restrict__ qlo,
    unsigned short* __restrict__ khi, unsigned short* __restrict__ klo,
    unsigned short* __restrict__ vt)
{
    __shared__ __align__(16) unsigned char smem[49152];   // 2 x 24KB stage
    const int tid = threadIdx.x;
    const int w = tid >> 6, lane = tid & 63;
    const int l31 = lane & 31, kh = lane >> 5;     // 32x32 frag: col(token), k-half
    const int row0 = (int)blockIdx.x * 32;
    const int tok = row0 + l31;                    // this lane's token (B col)

    f32x16 acc;
    #pragma unroll
    for (int r = 0; r < 16; r++) acc[r] = 0.f;

    // lane's x base: chunk c of step e0 reads x[tok][e0 + c*16 + kh*8 ..+8]
    const float* xr = x + (size_t)tok * EE + kh * 8;

    // DMA lane decomposition: 8 rows x 8 chunks per 1KB group; slot sl of row
    // r_l holds chunk sl^r_l (hi chunks 0..3 = e-sub 0..3, lo chunks 4..7)
    const int r_l = lane >> 3, sl = lane & 7;
    const int cg = sl ^ r_l;
    const unsigned short* mat = (cg < 4) ? wt_hi : wt_lo;
    const int ce = (cg & 3) * 8;

    auto dma_step = [&](int e0, unsigned char* dst) {
        #pragma unroll
        for (int ii = 0; ii < 4; ii++) {
            const int i = w * 4 + ii;              // 0..23: 8-row group
            const int row = i * 8 + r_l;           // 0..191
            async_copy16(mat + (size_t)row * EE + e0 + ce, dst + i * 1024);
        }
    };

    // swizzled read slots (bytes in a 128B row): chunk idx c*2+kh (hi), +4 (lo)
    const int r7 = lane & 7;
    const int sh0 = ((0 + kh) ^ r7) * 16;          // c=0 hi
    const int sl0 = ((4 + kh) ^ r7) * 16;          // c=0 lo
    const int sh1 = ((2 + kh) ^ r7) * 16;          // c=1 hi
    const int sl1 = ((6 + kh) ^ r7) * 16;          // c=1 lo

    // prologue: stage 0 + x(0)
    dma_step(0, smem);
    float4 c0 = *(const float4*)(xr + 0);
    float4 c1 = *(const float4*)(xr + 4);
    float4 c2 = *(const float4*)(xr + 16);
    float4 c3 = *(const float4*)(xr + 20);
    float4 n0, n1, n2, n3;

    for (int s = 0; s < 32; s++) {
        wait_vm<0>();                              // own DMA(s) + x(s) landed
        __builtin_amdgcn_s_barrier();              // stage s valid; s-1 reads done
        if (s < 31) {
            const int e1 = (s + 1) * 32;
            dma_step(e1, smem + ((s + 1) & 1) * 24576);
            n0 = *(const float4*)(xr + e1);
            n1 = *(const float4*)(xr + e1 + 4);
            n2 = *(const float4*)(xr + e1 + 16);
            n3 = *(const float4*)(xr + e1 + 20);
        }

        // convert x(s) -> split-bf16 B-frags (chunks 0,1 of this 32-e step)
        float f0[8] = {c0.x, c0.y, c0.z, c0.w, c1.x, c1.y, c1.z, c1.w};
        float f1[8] = {c2.x, c2.y, c2.z, c2.w, c3.x, c3.y, c3.z, c3.w};
        bf16x8 bh0, bl0, bh1, bl1;
        #pragma unroll
        for (int jj = 0; jj < 8; jj++) {
            unsigned short hb;
            hb = f2bf_rne(f0[jj]); bh0[jj] = (short)hb;
            bl0[jj] = (short)f2bf_rne(f0[jj] - bf2f(hb));
            hb = f2bf_rne(f1[jj]); bh1[jj] = (short)hb;
            bl1[jj] = (short)f2bf_rne(f1[jj] - bf2f(hb));
        }

        const unsigned char* rb =
            smem + (s & 1) * 24576 + (w * 32 + l31) * 128;
        bf16x8 Ah0 = *(const bf16x8*)(rb + sh0);
        bf16x8 Al0 = *(const bf16x8*)(rb + sl0);
        bf16x8 Ah1 = *(const bf16x8*)(rb + sh1);
        bf16x8 Al1 = *(const bf16x8*)(rb + sl1);
        acc = MFMA32(Ah0, bh0, acc);
        acc = MFMA32(Ah0, bl0, acc);
        acc = MFMA32(Al0, bh0, acc);
        acc = MFMA32(Ah1, bh1, acc);
        acc = MFMA32(Ah1, bl1, acc);
        acc = MFMA32(Al1, bh1, acc);
        c0 = n0; c1 = n1; c2 = n2; c3 = n3;
    }

    // ---- epilogue: wave w owns h-rows [w*32, w*32+32).
    // C layout (32x32): col = l31, row = (r&3) + 8*(r>>2) + 4*kh
    // -> reg group g (r = 4g..4g+3) is 4 consecutive h at w*32 + 8g + 4kh.
    const int bb = tok >> 12, tloc = tok & 4095;
    if (w < 4) {                                   // q (w 0,1) / k (w 2,3)
        unsigned short* hi_p = (w < 2) ? qhi : khi;
        unsigned short* lo_p = (w < 2) ? qlo : klo;
        const int hbase = (w & 1) * 32;
        #pragma unroll
        for (int g = 0; g < 4; g++) {
            const int h = hbase + g * 8 + kh * 4;
            ushort4 hi4, lo4; unsigned short hb; float f;
            f = acc[g * 4 + 0]; hb = f2bf_rne(f); hi4.x = hb; lo4.x = f2bf_rne(f - bf2f(hb));
            f = acc[g * 4 + 1]; hb = f2bf_rne(f); hi4.y = hb; lo4.y = f2bf_rne(f - bf2f(hb));
            f = acc[g * 4 + 2]; hb = f2bf_rne(f); hi4.z = hb; lo4.z = f2bf_rne(f - bf2f(hb));
            f = acc[g * 4 + 3]; hb = f2bf_rne(f); hi4.w = hb; lo4.w = f2bf_rne(f - bf2f(hb));
            const size_t o = (size_t)tok * 64 + h;
            *(ushort4*)(hi_p + o) = hi4;
            *(ushort4*)(lo_p + o) = lo4;
        }
    } else {                                       // v (w 4,5), transposed [h][t]
        const int hbase = (w - 4) * 32;
        #pragma unroll
        for (int r = 0; r < 16; r++) {
            const int H = hbase + (r & 3) + 8 * (r >> 2) + 4 * kh;
            vt[((size_t)(bb * 64 + H) << 12) + tloc] = f2bf_rne(acc[r]);
        }
    }
}

// ---------------------------------------------------------------------------
// Kernel 2: flash attention (unchanged from R9): S^T form, static-M softmax,
// uniform blocks — 512-thr block handles pair (gA=bx, gB=127-bx) in two
// sequential split-K-8 phases -> every block runs exactly 129 tiles.
// ---------------------------------------------------------------------------
__global__ __launch_bounds__(512) void flash_kernel(
    const unsigned short* __restrict__ qhi, const unsigned short* __restrict__ qlo,
    const unsigned short* __restrict__ khi, const unsigned short* __restrict__ klo,
    const unsigned short* __restrict__ vt, float* __restrict__ out)
{
    __shared__ __align__(16) unsigned char smem[151552];
    const int tid = threadIdx.x;
    const int w = tid >> 6, lane = tid & 63;
    const int quad = lane >> 4, li = lane & 15;
    const int bx = (int)blockIdx.x;                // 0..63: pair (bx, 127-bx)
    const int b = (int)blockIdx.y;                 // batch
    const float SM = 20.0f;                        // static softmax offset

    const unsigned short* kb_hi = khi + ((size_t)b << 18);
    const unsigned short* kb_lo = klo + ((size_t)b << 18);
    const unsigned short* vtb   = vt  + ((size_t)b << 18) + (size_t)li * 4096 + quad * 8;

    unsigned char* kbase = smem + w * 16384;       // wave-private 2x8KB
    unsigned short* PsA = (unsigned short*)(smem + 131072 + w * 2560);
    unsigned short* PsB = PsA + 640;
    float* Op = (float*)smem;                      // [8][64][33] (phase epilogue)
    float* Ml = (float*)(smem + 67584);            // [8][32]

    const int r_l4 = lane >> 4, s16 = lane & 15;
    const int slh0 = ((quad)      ^ li) * 8;       // K hi, h 0..31
    const int slh1 = ((4 + quad)  ^ li) * 8;       // K hi, h 32..63
    const int sll0 = ((8 + quad)  ^ li) * 8;       // K lo, h 0..31
    const int sll1 = ((12 + quad) ^ li) * 8;       // K lo, h 32..63

    auto dma_tile = [&](int k0, unsigned char* dst) {
        #pragma unroll
        for (int i = 0; i < 8; i++) {
            const int row = i * 4 + r_l4;          // 0..31
            const int c = s16 ^ (row & 15);
            const unsigned short* src = (c < 8)
                ? kb_hi + (size_t)(k0 + row) * 64 + c * 8
                : kb_lo + (size_t)(k0 + row) * 64 + (c - 8) * 8;
            async_copy16(src, dst + i * 1024);
        }
    };

    #pragma unroll 1
    for (int phase = 0; phase < 2; phase++) {
        const int g = phase ? (127 - bx) : bx;
        const int q0 = g * 32;
        const int n_kt = g + 1;                    // 32-token causal K-tiles
        const int tok0 = q0 + li, tok1 = tok0 + 16;

        const size_t qo0 = ((size_t)(b << 12) + tok0) * 64 + quad * 8;
        const size_t qo1 = qo0 + 16 * 64;
        const bf16x8 QhA0 = *(const bf16x8*)(qhi + qo0);
        const bf16x8 QhA1 = *(const bf16x8*)(qhi + qo0 + 32);
        const bf16x8 QlA0 = *(const bf16x8*)(qlo + qo0);
        const bf16x8 QlA1 = *(const bf16x8*)(qlo + qo0 + 32);
        const bf16x8 QhB0 = *(const bf16x8*)(qhi + qo1);
        const bf16x8 QhB1 = *(const bf16x8*)(qhi + qo1 + 32);
        const bf16x8 QlB0 = *(const bf16x8*)(qlo + qo1);
        const bf16x8 QlB1 = *(const bf16x8*)(qlo + qo1 + 32);

        f32x4 accA[4], accB[4];
        #pragma unroll
        for (int mt = 0; mt < 4; mt++) {
            accA[mt] = (f32x4){0.f, 0.f, 0.f, 0.f};
            accB[mt] = (f32x4){0.f, 0.f, 0.f, 0.f};
        }
        float lA = 0.f, lB = 0.f;

        bf16x8 Vc[4], Vn[4];
        int bufp = 0;
        if (w < n_kt) {                            // prologue for tile w
            dma_tile(w * 32, kbase);
            #pragma unroll
            for (int hf = 0; hf < 4; hf++)
                Vc[hf] = *(const bf16x8*)(vtb + (size_t)hf * 65536 + w * 32);
        }

        for (int kt = w; kt < n_kt; kt += 8) {
            const int k0 = kt * 32;

            if (kt + 8 < n_kt) {                   // prefetch next tile
                dma_tile((kt + 8) * 32, kbase + (bufp ^ 1) * 8192);
                #pragma unroll
                for (int hf = 0; hf < 4; hf++)
                    Vn[hf] = *(const bf16x8*)(vtb + (size_t)hf * 65536 + (kt + 8) * 32);
                wait_vm<12>();                     // drain current, keep prefetch
            } else {
                wait_vm<0>();
            }
            const unsigned short* Kw = (const unsigned short*)(kbase + bufp * 8192);

            f32x4 sA[2], sB[2];
            #pragma unroll
            for (int jf = 0; jf < 2; jf++) {
                const unsigned short* rb = Kw + (jf * 16 + li) * 128;  // 256B rows
                bf16x8 Kh0 = *(const bf16x8*)(rb + slh0);
                bf16x8 Kh1 = *(const bf16x8*)(rb + slh1);
                bf16x8 Kl0 = *(const bf16x8*)(rb + sll0);
                bf16x8 Kl1 = *(const bf16x8*)(rb + sll1);
                f32x4 a = (f32x4){0.f, 0.f, 0.f, 0.f};
                a = MFMA16(Kh0, QhA0, a);
                a = MFMA16(Kh1, QhA1, a);
                a = MFMA16(Kh0, QlA0, a);
                a = MFMA16(Kh1, QlA1, a);
                a = MFMA16(Kl0, QhA0, a);
                a = MFMA16(Kl1, QhA1, a);
                sA[jf] = a;
                f32x4 c2 = (f32x4){0.f, 0.f, 0.f, 0.f};
                c2 = MFMA16(Kh0, QhB0, c2);
                c2 = MFMA16(Kh1, QhB1, c2);
                c2 = MFMA16(Kh0, QlB0, c2);
                c2 = MFMA16(Kh1, QlB1, c2);
                c2 = MFMA16(Kl0, QhB0, c2);
                c2 = MFMA16(Kl1, QhB1, c2);
                sB[jf] = c2;
            }

            if (kt == n_kt - 1) {                  // causal mask, diagonal tile
                #pragma unroll
                for (int jf = 0; jf < 2; jf++)
                    #pragma unroll
                    for (int r = 0; r < 4; r++) {
                        const int j = k0 + jf * 16 + quad * 4 + r;
                        if (j > tok0) sA[jf][r] = -1e30f;
                        if (j > tok1) sB[jf][r] = -1e30f;
                    }
            }

            #pragma unroll
            for (int jf = 0; jf < 2; jf++)
                #pragma unroll
                for (int r = 0; r < 4; r++) {
                    sA[jf][r] = __expf(sA[jf][r] - SM); lA += sA[jf][r];
                    sB[jf][r] = __expf(sB[jf][r] - SM); lB += sB[jf][r];
                }

            #pragma unroll
            for (int jf = 0; jf < 2; jf++) {
                ushort4 pa, pb;
                pa.x = f2bf_rne(sA[jf][0]); pa.y = f2bf_rne(sA[jf][1]);
                pa.z = f2bf_rne(sA[jf][2]); pa.w = f2bf_rne(sA[jf][3]);
                pb.x = f2bf_rne(sB[jf][0]); pb.y = f2bf_rne(sB[jf][1]);
                pb.z = f2bf_rne(sB[jf][2]); pb.w = f2bf_rne(sB[jf][3]);
                *(ushort4*)&PsA[li * 40 + jf * 16 + quad * 4] = pa;
                *(ushort4*)&PsB[li * 40 + jf * 16 + quad * 4] = pb;
            }
            const bf16x8 PA = *(const bf16x8*)&PsA[li * 40 + quad * 8];
            const bf16x8 PB = *(const bf16x8*)&PsB[li * 40 + quad * 8];

            #pragma unroll
            for (int hf = 0; hf < 4; hf++) {
                accA[hf] = MFMA16(Vc[hf], PA, accA[hf]);
                accB[hf] = MFMA16(Vc[hf], PB, accB[hf]);
            }
            #pragma unroll
            for (int hf = 0; hf < 4; hf++) Vc[hf] = Vn[hf];
            bufp ^= 1;
        }

        lA += __shfl_xor(lA, 16); lA += __shfl_xor(lA, 32);
        lB += __shfl_xor(lB, 16); lB += __shfl_xor(lB, 32);

        __syncthreads();                           // all waves done with Kbuf
        #pragma unroll
        for (int mt = 0; mt < 4; mt++)
            #pragma unroll
            for (int r = 0; r < 4; r++) {
                Op[(size_t)w * 2112 + (mt * 16 + quad * 4 + r) * 33 + li]      = accA[mt][r];
                Op[(size_t)w * 2112 + (mt * 16 + quad * 4 + r) * 33 + li + 16] = accB[mt][r];
            }
        if (quad == 0) {
            Ml[w * 32 + li]      = lA;
            Ml[w * 32 + 16 + li] = lB;
        }
        __syncthreads();

        const int i  = tid >> 4;                   // 0..31
        const int hc = (tid & 15) * 4;
        float l = 0.f;
        #pragma unroll
        for (int ww = 0; ww < 8; ww++) l += Ml[ww * 32 + i];
        const float inv = 1.0f / (l * 8.0f);       // /= sqrt(64) after softmax
        float4 o = {0.f, 0.f, 0.f, 0.f};
        #pragma unroll
        for (int ww = 0; ww < 8; ww++) {
            const float* base = Op + (size_t)ww * 2112;
            o.x += base[(hc + 0) * 33 + i];
            o.y += base[(hc + 1) * 33 + i];
            o.z += base[(hc + 2) * 33 + i];
            o.w += base[(hc + 3) * 33 + i];
        }
        o.x *= inv; o.y *= inv; o.z *= inv; o.w *= inv;
        *(float4*)(out + ((size_t)(b << 12) + q0 + i) * 64 + hc) = o;
        __syncthreads();                           // Opart free before next phase
    }
}

// ---------------------------------------------------------------------------
extern "C" void kernel_launch(void* const* d_in, const int* in_sizes, int n_in,
                              void* d_out, int out_size, void* d_ws, size_t ws_size,
                              hipStream_t stream)
{
    const float* x  = (const float*)d_in[0];
    const float* Wq = (const float*)d_in[1];
    const float* Wk = (const float*)d_in[2];
    const float* Wv = (const float*)d_in[3];
    float* out = (float*)d_out;

    const size_t n_tok = (size_t)BB * TT * HH;    // 1,048,576
    unsigned short* qhi = (unsigned short*)d_ws;
    unsigned short* qlo = qhi + n_tok;
    unsigned short* khi = qlo + n_tok;
    unsigned short* klo = khi + n_tok;
    unsigned short* vt  = klo + n_tok;            // [B][64][4096]
    unsigned short* wt_hi = vt + n_tok;           // [192][1024]
    unsigned short* wt_lo = wt_hi + 192 * 1024;   // total ~10.75 MB

    wprep_kernel<<<48, 256, 0, stream>>>(Wq, Wk, Wv, wt_hi, wt_lo);
    proj_kernel<<<(BB * TT) / 32, 384, 0, stream>>>(x, wt_hi, wt_lo,
                                                    qhi, qlo, khi, klo, vt);
    flash_kernel<<<dim3(64, BB), 512, 0, stream>>>(qhi, qlo, khi, klo, vt, out);
}

// Round 12
// 178.335 us; speedup vs baseline: 1.1665x; 1.1665x over previous
//
#include <hip/hip_runtime.h>
#include <math.h>

#define BB 4
#define TT 4096
#define EE 1024
#define HH 64

typedef __attribute__((ext_vector_type(8))) short bf16x8;   // 8 bf16 = 4 VGPRs
typedef __attribute__((ext_vector_type(4))) float f32x4;

#define MFMA16(a, b, c) __builtin_amdgcn_mfma_f32_16x16x32_bf16(a, b, c, 0, 0, 0)

__device__ __forceinline__ unsigned short f2bf_rne(float f) {
    unsigned u = __float_as_uint(f);
    unsigned r = u + 0x7fffu + ((u >> 16) & 1u);   // round-to-nearest-even
    return (unsigned short)(r >> 16);
}
__device__ __forceinline__ float bf2f(unsigned short h) {
    return __uint_as_float(((unsigned)h) << 16);
}

// async 16B global->LDS DMA; LDS dest = base + lane*16 (wave-uniform base)
__device__ __forceinline__ void async_copy16(const void* g, void* l) {
    __builtin_amdgcn_global_load_lds(
        (const __attribute__((address_space(1))) void*)g,
        (__attribute__((address_space(3))) void*)l, 16, 0, 0);
}
// wait until <= N vector-memory ops outstanding (lgkm/exp untouched);
// vmcnt is a 6-bit split field: [3:0] and [15:14]
template<int N>
__device__ __forceinline__ void wait_vm() {
    __builtin_amdgcn_s_waitcnt(0x0f70 | (N & 15) | ((N >> 4) << 14));
}

// ---------------------------------------------------------------------------
// Kernel 0: W prep via LDS transpose.  wt_hi/lo[h192][e] = split-bf16 of
// W{q|k|v}[e][h].  48 blocks.  (unchanged)
// ---------------------------------------------------------------------------
__global__ __launch_bounds__(256) void wprep_kernel(
    const float* __restrict__ Wq, const float* __restrict__ Wk,
    const float* __restrict__ Wv,
    unsigned short* __restrict__ wt_hi, unsigned short* __restrict__ wt_lo)
{
    __shared__ float ts[64][65];
    const int which = blockIdx.x >> 4;
    const int e0 = (blockIdx.x & 15) * 64;
    const float* W = (which == 0) ? Wq : ((which == 1) ? Wk : Wv);
    const int t = threadIdx.x;
    const int h = t & 63;
    #pragma unroll
    for (int p = 0; p < 16; p++) {
        const int er = (t >> 6) + p * 4;
        ts[er][h] = W[(size_t)(e0 + er) * 64 + h];
    }
    __syncthreads();
    const int ew = t & 63;
    #pragma unroll
    for (int p = 0; p < 16; p++) {
        const int hh = (t >> 6) + p * 4;
        const float f = ts[ew][hh];
        const unsigned short hb = f2bf_rne(f);
        const unsigned short lb = f2bf_rne(f - bf2f(hb));
        const size_t o = (size_t)(which * 64 + hh) * 1024 + e0 + ew;
        wt_hi[o] = hb;
        wt_lo[o] = lb;
    }
}

// ---------------------------------------------------------------------------
// Kernel 1: QKV projection — R9 structure (best measured: triple-buffered
// DMA stage, 8 waves = (tg)x(eh), 1 block/CU) with DOUBLED B: each wave
// carries TWO 16-token B-fragments, so the same 24 ds_read_b128/step feed
// 72 MFMA (R11 post-mortem: LDS read stream is proj's largest pipe cost;
// amortize it over 2x tokens).  Block = 128 tokens, 128 blocks (W L2
// traffic halves).  launch_bounds(512,2): acc liveness needs ~190 VGPRs.
// ---------------------------------------------------------------------------
__global__ __launch_bounds__(512, 2) void proj_kernel(
    const float* __restrict__ x,
    const unsigned short* __restrict__ wt_hi, const unsigned short* __restrict__ wt_lo,
    unsigned short* __restrict__ qhi, unsigned short* __restrict__ qlo,
    unsigned short* __restrict__ khi, unsigned short* __restrict__ klo,
    unsigned short* __restrict__ vt)
{
    __shared__ __align__(16) unsigned char smem[147456];  // 3x48KB stage; Red union
    const int tid = threadIdx.x;
    const int w = tid >> 6, lane = tid & 63;
    const int quad = lane >> 4, li = lane & 15;
    const int tg = w & 3, eh = w >> 2;
    const int row0 = (int)blockIdx.x * 128;
    const int tokA = row0 + tg * 32 + li;          // B-frag A token
    const int tokB = tokA + 16;                    // B-frag B token

    f32x4 acc0[12], acc1[12];
    #pragma unroll
    for (int mt = 0; mt < 12; mt++) {
        acc0[mt] = (f32x4){0.f, 0.f, 0.f, 0.f};
        acc1[mt] = (f32x4){0.f, 0.f, 0.f, 0.f};
    }

    const float* xrA = x + (size_t)tokA * EE + eh * 512 + quad * 8;
    const float* xrB = x + (size_t)tokB * EE + eh * 512 + quad * 8;

    // DMA lane decomposition: 8 rows x 8 chunks per 1KB group; slot s = chunk s^row
    const int r_l = lane >> 3, sl = lane & 7;
    const int cg = sl ^ r_l;
    const unsigned short* mat = (cg < 4) ? wt_hi : wt_lo;
    const int ce = (cg & 3) * 8;
    const int sA = (quad ^ (li & 7)) * 8;          // hi, swizzled read slot
    const int sB = ((4 + quad) ^ (li & 7)) * 8;    // lo

    auto dma_step = [&](int e0, unsigned char* dstbase) {
        #pragma unroll
        for (int ii = 0; ii < 6; ii++) {
            const int i = w * 6 + ii;              // 0..47
            const int ehc = i / 24;
            const int within = i % 24;
            const int row = within * 8 + r_l;      // 0..191
            const unsigned short* src = mat + (size_t)row * EE + ehc * 512 + e0 + ce;
            async_copy16(src, dstbase + ehc * 24576 + within * 1024);
        }
    };

    // prologue: two steps in flight (FIFO: dma(0),x(0),dma(1),x(1))
    dma_step(0, smem);
    float4 a0 = *(const float4*)(xrA + 0), a1 = *(const float4*)(xrA + 4);
    float4 b0 = *(const float4*)(xrB + 0), b1 = *(const float4*)(xrB + 4);
    dma_step(32, smem + 49152);
    float4 a2 = *(const float4*)(xrA + 32), a3 = *(const float4*)(xrA + 36);
    float4 b2 = *(const float4*)(xrB + 32), b3 = *(const float4*)(xrB + 36);
    float4 a4, a5, b4, b5;

    for (int s = 0; s < 16; s++) {
        const int e0 = s * 32;
        if (s + 2 < 16) {
            dma_step(e0 + 64, smem + ((s + 2) % 3) * 49152);
            a4 = *(const float4*)(xrA + e0 + 64); a5 = *(const float4*)(xrA + e0 + 68);
            b4 = *(const float4*)(xrB + e0 + 64); b5 = *(const float4*)(xrB + e0 + 68);
            wait_vm<20>();                         // drain step-s set; keep s+1,s+2
        } else if (s + 1 < 16) {
            wait_vm<10>();                         // keep step s+1 set
        } else {
            wait_vm<0>();
        }
        __builtin_amdgcn_s_barrier();              // stage s valid block-wide

        float fA[8] = {a0.x, a0.y, a0.z, a0.w, a1.x, a1.y, a1.z, a1.w};
        float fB[8] = {b0.x, b0.y, b0.z, b0.w, b1.x, b1.y, b1.z, b1.w};
        bf16x8 bhA, blA, bhB, blB;
        #pragma unroll
        for (int jj = 0; jj < 8; jj++) {
            unsigned short hb;
            hb = f2bf_rne(fA[jj]); bhA[jj] = (short)hb;
            blA[jj] = (short)f2bf_rne(fA[jj] - bf2f(hb));
            hb = f2bf_rne(fB[jj]); bhB[jj] = (short)hb;
            blB[jj] = (short)f2bf_rne(fB[jj] - bf2f(hb));
        }
        const unsigned short* Wbase =
            (const unsigned short*)(smem + (s % 3) * 49152 + eh * 24576);
        #pragma unroll
        for (int mt = 0; mt < 12; mt++) {
            const unsigned short* rb = Wbase + (mt * 16 + li) * 64;  // 128B rows
            bf16x8 Ah = *(const bf16x8*)(rb + sA);
            bf16x8 Al = *(const bf16x8*)(rb + sB);
            acc0[mt] = MFMA16(Ah, bhA, acc0[mt]);
            acc0[mt] = MFMA16(Ah, blA, acc0[mt]);
            acc0[mt] = MFMA16(Al, bhA, acc0[mt]);
            acc1[mt] = MFMA16(Ah, bhB, acc1[mt]);
            acc1[mt] = MFMA16(Ah, blB, acc1[mt]);
            acc1[mt] = MFMA16(Al, bhB, acc1[mt]);
        }
        __builtin_amdgcn_s_barrier();              // all done reading buf s%3
        a0 = a2; a1 = a3; a2 = a4; a3 = a5;
        b0 = b2; b1 = b3; b2 = b4; b3 = b5;
    }

    // ---- merge e-halves via Red union ([8 sg][192 h][17 tok] f32 = 102 KB) ----
    // sub-group sg = tg*2 + {0:A, 1:B}; C layout: row h = mt*16+quad*4+r, col=li
    float* Red = (float*)smem;
    if (eh == 1) {
        #pragma unroll
        for (int mt = 0; mt < 12; mt++)
            #pragma unroll
            for (int r = 0; r < 4; r++) {
                Red[(size_t)((tg * 2 + 0) * 192 + mt * 16 + quad * 4 + r) * 17 + li] = acc0[mt][r];
                Red[(size_t)((tg * 2 + 1) * 192 + mt * 16 + quad * 4 + r) * 17 + li] = acc1[mt][r];
            }
    }
    __syncthreads();
    if (eh == 0) {
        #pragma unroll
        for (int mt = 0; mt < 12; mt++)
            #pragma unroll
            for (int r = 0; r < 4; r++) {
                acc0[mt][r] += Red[(size_t)((tg * 2 + 0) * 192 + mt * 16 + quad * 4 + r) * 17 + li];
                acc1[mt][r] += Red[(size_t)((tg * 2 + 1) * 192 + mt * 16 + quad * 4 + r) * 17 + li];
            }
        #pragma unroll
        for (int half = 0; half < 2; half++) {
            const int tok = half ? tokB : tokA;
            const int bb = tok >> 12, tloc = tok & 4095;
            #pragma unroll
            for (int mt = 0; mt < 12; mt++) {
                f32x4 av;
                #pragma unroll
                for (int r = 0; r < 4; r++)
                    av[r] = half ? acc1[mt][r] : acc0[mt][r];
                if (mt < 8) {
                    const int h = (mt & 3) * 16 + quad * 4;
                    ushort4 hi4, lo4; unsigned short hb; float f;
                    f = av[0]; hb = f2bf_rne(f); hi4.x = hb; lo4.x = f2bf_rne(f - bf2f(hb));
                    f = av[1]; hb = f2bf_rne(f); hi4.y = hb; lo4.y = f2bf_rne(f - bf2f(hb));
                    f = av[2]; hb = f2bf_rne(f); hi4.z = hb; lo4.z = f2bf_rne(f - bf2f(hb));
                    f = av[3]; hb = f2bf_rne(f); hi4.w = hb; lo4.w = f2bf_rne(f - bf2f(hb));
                    const size_t o = (size_t)tok * 64 + h;
                    if (mt < 4) { *(ushort4*)(qhi + o) = hi4; *(ushort4*)(qlo + o) = lo4; }
                    else        { *(ushort4*)(khi + o) = hi4; *(ushort4*)(klo + o) = lo4; }
                } else {
                    const int hv = (mt - 8) * 16 + quad * 4;
                    #pragma unroll
                    for (int r = 0; r < 4; r++)
                        vt[((size_t)(bb * 64 + hv + r) << 12) + tloc] = f2bf_rne(av[r]);
                }
            }
        }
    }
}

// ---------------------------------------------------------------------------
// Kernel 2: flash attention (unchanged from R9): S^T form, static-M softmax,
// uniform blocks — 512-thr block handles pair (gA=bx, gB=127-bx) in two
// sequential split-K-8 phases -> every block runs exactly 129 tiles.
// ---------------------------------------------------------------------------
__global__ __launch_bounds__(512) void flash_kernel(
    const unsigned short* __restrict__ qhi, const unsigned short* __restrict__ qlo,
    const unsigned short* __restrict__ khi, const unsigned short* __restrict__ klo,
    const unsigned short* __restrict__ vt, float* __restrict__ out)
{
    __shared__ __align__(16) unsigned char smem[151552];
    const int tid = threadIdx.x;
    const int w = tid >> 6, lane = tid & 63;
    const int quad = lane >> 4, li = lane & 15;
    const int bx = (int)blockIdx.x;                // 0..63: pair (bx, 127-bx)
    const int b = (int)blockIdx.y;                 // batch
    const float SM = 20.0f;                        // static softmax offset

    const unsigned short* kb_hi = khi + ((size_t)b << 18);
    const unsigned short* kb_lo = klo + ((size_t)b << 18);
    const unsigned short* vtb   = vt  + ((size_t)b << 18) + (size_t)li * 4096 + quad * 8;

    unsigned char* kbase = smem + w * 16384;       // wave-private 2x8KB
    unsigned short* PsA = (unsigned short*)(smem + 131072 + w * 2560);
    unsigned short* PsB = PsA + 640;
    float* Op = (float*)smem;                      // [8][64][33] (phase epilogue)
    float* Ml = (float*)(smem + 67584);            // [8][32]

    const int r_l4 = lane >> 4, s16 = lane & 15;
    const int slh0 = ((quad)      ^ li) * 8;       // K hi, h 0..31
    const int slh1 = ((4 + quad)  ^ li) * 8;       // K hi, h 32..63
    const int sll0 = ((8 + quad)  ^ li) * 8;       // K lo, h 0..31
    const int sll1 = ((12 + quad) ^ li) * 8;       // K lo, h 32..63

    auto dma_tile = [&](int k0, unsigned char* dst) {
        #pragma unroll
        for (int i = 0; i < 8; i++) {
            const int row = i * 4 + r_l4;          // 0..31
            const int c = s16 ^ (row & 15);
            const unsigned short* src = (c < 8)
                ? kb_hi + (size_t)(k0 + row) * 64 + c * 8
                : kb_lo + (size_t)(k0 + row) * 64 + (c - 8) * 8;
            async_copy16(src, dst + i * 1024);
        }
    };

    #pragma unroll 1
    for (int phase = 0; phase < 2; phase++) {
        const int g = phase ? (127 - bx) : bx;
        const int q0 = g * 32;
        const int n_kt = g + 1;                    // 32-token causal K-tiles
        const int tok0 = q0 + li, tok1 = tok0 + 16;

        const size_t qo0 = ((size_t)(b << 12) + tok0) * 64 + quad * 8;
        const size_t qo1 = qo0 + 16 * 64;
        const bf16x8 QhA0 = *(const bf16x8*)(qhi + qo0);
        const bf16x8 QhA1 = *(const bf16x8*)(qhi + qo0 + 32);
        const bf16x8 QlA0 = *(const bf16x8*)(qlo + qo0);
        const bf16x8 QlA1 = *(const bf16x8*)(qlo + qo0 + 32);
        const bf16x8 QhB0 = *(const bf16x8*)(qhi + qo1);
        const bf16x8 QhB1 = *(const bf16x8*)(qhi + qo1 + 32);
        const bf16x8 QlB0 = *(const bf16x8*)(qlo + qo1);
        const bf16x8 QlB1 = *(const bf16x8*)(qlo + qo1 + 32);

        f32x4 accA[4], accB[4];
        #pragma unroll
        for (int mt = 0; mt < 4; mt++) {
            accA[mt] = (f32x4){0.f, 0.f, 0.f, 0.f};
            accB[mt] = (f32x4){0.f, 0.f, 0.f, 0.f};
        }
        float lA = 0.f, lB = 0.f;

        bf16x8 Vc[4], Vn[4];
        int bufp = 0;
        if (w < n_kt) {                            // prologue for tile w
            dma_tile(w * 32, kbase);
            #pragma unroll
            for (int hf = 0; hf < 4; hf++)
                Vc[hf] = *(const bf16x8*)(vtb + (size_t)hf * 65536 + w * 32);
        }

        for (int kt = w; kt < n_kt; kt += 8) {
            const int k0 = kt * 32;

            if (kt + 8 < n_kt) {                   // prefetch next tile
                dma_tile((kt + 8) * 32, kbase + (bufp ^ 1) * 8192);
                #pragma unroll
                for (int hf = 0; hf < 4; hf++)
                    Vn[hf] = *(const bf16x8*)(vtb + (size_t)hf * 65536 + (kt + 8) * 32);
                wait_vm<12>();                     // drain current, keep prefetch
            } else {
                wait_vm<0>();
            }
            const unsigned short* Kw = (const unsigned short*)(kbase + bufp * 8192);

            f32x4 sA[2], sB[2];
            #pragma unroll
            for (int jf = 0; jf < 2; jf++) {
                const unsigned short* rb = Kw + (jf * 16 + li) * 128;  // 256B rows
                bf16x8 Kh0 = *(const bf16x8*)(rb + slh0);
                bf16x8 Kh1 = *(const bf16x8*)(rb + slh1);
                bf16x8 Kl0 = *(const bf16x8*)(rb + sll0);
                bf16x8 Kl1 = *(const bf16x8*)(rb + sll1);
                f32x4 a = (f32x4){0.f, 0.f, 0.f, 0.f};
                a = MFMA16(Kh0, QhA0, a);
                a = MFMA16(Kh1, QhA1, a);
                a = MFMA16(Kh0, QlA0, a);
                a = MFMA16(Kh1, QlA1, a);
                a = MFMA16(Kl0, QhA0, a);
                a = MFMA16(Kl1, QhA1, a);
                sA[jf] = a;
                f32x4 c2 = (f32x4){0.f, 0.f, 0.f, 0.f};
                c2 = MFMA16(Kh0, QhB0, c2);
                c2 = MFMA16(Kh1, QhB1, c2);
                c2 = MFMA16(Kh0, QlB0, c2);
                c2 = MFMA16(Kh1, QlB1, c2);
                c2 = MFMA16(Kl0, QhB0, c2);
                c2 = MFMA16(Kl1, QhB1, c2);
                sB[jf] = c2;
            }

            if (kt == n_kt - 1) {                  // causal mask, diagonal tile
                #pragma unroll
                for (int jf = 0; jf < 2; jf++)
                    #pragma unroll
                    for (int r = 0; r < 4; r++) {
                        const int j = k0 + jf * 16 + quad * 4 + r;
                        if (j > tok0) sA[jf][r] = -1e30f;
                        if (j > tok1) sB[jf][r] = -1e30f;
                    }
            }

            #pragma unroll
            for (int jf = 0; jf < 2; jf++)
                #pragma unroll
                for (int r = 0; r < 4; r++) {
                    sA[jf][r] = __expf(sA[jf][r] - SM); lA += sA[jf][r];
                    sB[jf][r] = __expf(sB[jf][r] - SM); lB += sB[jf][r];
                }

            #pragma unroll
            for (int jf = 0; jf < 2; jf++) {
                ushort4 pa, pb;
                pa.x = f2bf_rne(sA[jf][0]); pa.y = f2bf_rne(sA[jf][1]);
                pa.z = f2bf_rne(sA[jf][2]); pa.w = f2bf_rne(sA[jf][3]);
                pb.x = f2bf_rne(sB[jf][0]); pb.y = f2bf_rne(sB[jf][1]);
                pb.z = f2bf_rne(sB[jf][2]); pb.w = f2bf_rne(sB[jf][3]);
                *(ushort4*)&PsA[li * 40 + jf * 16 + quad * 4] = pa;
                *(ushort4*)&PsB[li * 40 + jf * 16 + quad * 4] = pb;
            }
            const bf16x8 PA = *(const bf16x8*)&PsA[li * 40 + quad * 8];
            const bf16x8 PB = *(const bf16x8*)&PsB[li * 40 + quad * 8];

            #pragma unroll
            for (int hf = 0; hf < 4; hf++) {
                accA[hf] = MFMA16(Vc[hf], PA, accA[hf]);
                accB[hf] = MFMA16(Vc[hf], PB, accB[hf]);
            }
            #pragma unroll
            for (int hf = 0; hf < 4; hf++) Vc[hf] = Vn[hf];
            bufp ^= 1;
        }

        lA += __shfl_xor(lA, 16); lA += __shfl_xor(lA, 32);
        lB += __shfl_xor(lB, 16); lB += __shfl_xor(lB, 32);

        __syncthreads();                           // all waves done with Kbuf
        #pragma unroll
        for (int mt = 0; mt < 4; mt++)
            #pragma unroll
            for (int r = 0; r < 4; r++) {
                Op[(size_t)w * 2112 + (mt * 16 + quad * 4 + r) * 33 + li]      = accA[mt][r];
                Op[(size_t)w * 2112 + (mt * 16 + quad * 4 + r) * 33 + li + 16] = accB[mt][r];
            }
        if (quad == 0) {
            Ml[w * 32 + li]      = lA;
            Ml[w * 32 + 16 + li] = lB;
        }
        __syncthreads();

        const int i  = tid >> 4;                   // 0..31
        const int hc = (tid & 15) * 4;
        float l = 0.f;
        #pragma unroll
        for (int ww = 0; ww < 8; ww++) l += Ml[ww * 32 + i];
        const float inv = 1.0f / (l * 8.0f);       // /= sqrt(64) after softmax
        float4 o = {0.f, 0.f, 0.f, 0.f};
        #pragma unroll
        for (int ww = 0; ww < 8; ww++) {
            const float* base = Op + (size_t)ww * 2112;
            o.x += base[(hc + 0) * 33 + i];
            o.y += base[(hc + 1) * 33 + i];
            o.z += base[(hc + 2) * 33 + i];
            o.w += base[(hc + 3) * 33 + i];
        }
        o.x *= inv; o.y *= inv; o.z *= inv; o.w *= inv;
        *(float4*)(out + ((size_t)(b << 12) + q0 + i) * 64 + hc) = o;
        __syncthreads();                           // Opart free before next phase
    }
}

// ---------------------------------------------------------------------------
extern "C" void kernel_launch(void* const* d_in, const int* in_sizes, int n_in,
                              void* d_out, int out_size, void* d_ws, size_t ws_size,
                              hipStream_t stream)
{
    const float* x  = (const float*)d_in[0];
    const float* Wq = (const float*)d_in[1];
    const float* Wk = (const float*)d_in[2];
    const float* Wv = (const float*)d_in[3];
    float* out = (float*)d_out;

    const size_t n_tok = (size_t)BB * TT * HH;    // 1,048,576
    unsigned short* qhi = (unsigned short*)d_ws;
    unsigned short* qlo = qhi + n_tok;
    unsigned short* khi = qlo + n_tok;
    unsigned short* klo = khi + n_tok;
    unsigned short* vt  = klo + n_tok;            // [B][64][4096]
    unsigned short* wt_hi = vt + n_tok;           // [192][1024]
    unsigned short* wt_lo = wt_hi + 192 * 1024;   // total ~10.75 MB

    wprep_kernel<<<48, 256, 0, stream>>>(Wq, Wk, Wv, wt_hi, wt_lo);
    proj_kernel<<<(BB * TT) / 128, 512, 0, stream>>>(x, wt_hi, wt_lo,
                                                     qhi, qlo, khi, klo, vt);
    flash_kernel<<<dim3(64, BB), 512, 0, stream>>>(qhi, qlo, khi, klo, vt, out);
}

// Round 13
// 162.216 us; speedup vs baseline: 1.2825x; 1.0994x over previous
//
#include <hip/hip_runtime.h>
#include <math.h>

#define BB 4
#define TT 4096
#define EE 1024
#define HH 64

typedef __attribute__((ext_vector_type(8))) short bf16x8;   // 8 bf16 = 4 VGPRs
typedef __attribute__((ext_vector_type(4))) float f32x4;

#define MFMA16(a, b, c) __builtin_amdgcn_mfma_f32_16x16x32_bf16(a, b, c, 0, 0, 0)

__device__ __forceinline__ unsigned short f2bf_rne(float f) {
    unsigned u = __float_as_uint(f);
    unsigned r = u + 0x7fffu + ((u >> 16) & 1u);   // round-to-nearest-even
    return (unsigned short)(r >> 16);
}
__device__ __forceinline__ float bf2f(unsigned short h) {
    return __uint_as_float(((unsigned)h) << 16);
}

// async 16B global->LDS DMA; LDS dest = base + lane*16 (wave-uniform base)
__device__ __forceinline__ void async_copy16(const void* g, void* l) {
    __builtin_amdgcn_global_load_lds(
        (const __attribute__((address_space(1))) void*)g,
        (__attribute__((address_space(3))) void*)l, 16, 0, 0);
}
// wait until <= N vector-memory ops outstanding (lgkm/exp untouched);
// vmcnt is a 6-bit split field: [3:0] and [15:14]
template<int N>
__device__ __forceinline__ void wait_vm() {
    __builtin_amdgcn_s_waitcnt(0x0f70 | (N & 15) | ((N >> 4) << 14));
}

// ---------------------------------------------------------------------------
// Kernel 0: W prep via LDS transpose.  wt_hi/lo[h192][e] = split-bf16 of
// W{q|k|v}[e][h].  48 blocks.  (R9-exact)
// ---------------------------------------------------------------------------
__global__ __launch_bounds__(256) void wprep_kernel(
    const float* __restrict__ Wq, const float* __restrict__ Wk,
    const float* __restrict__ Wv,
    unsigned short* __restrict__ wt_hi, unsigned short* __restrict__ wt_lo)
{
    __shared__ float ts[64][65];
    const int which = blockIdx.x >> 4;
    const int e0 = (blockIdx.x & 15) * 64;
    const float* W = (which == 0) ? Wq : ((which == 1) ? Wk : Wv);
    const int t = threadIdx.x;
    const int h = t & 63;
    #pragma unroll
    for (int p = 0; p < 16; p++) {
        const int er = (t >> 6) + p * 4;
        ts[er][h] = W[(size_t)(e0 + er) * 64 + h];
    }
    __syncthreads();
    const int ew = t & 63;
    #pragma unroll
    for (int p = 0; p < 16; p++) {
        const int hh = (t >> 6) + p * 4;
        const float f = ts[ew][hh];
        const unsigned short hb = f2bf_rne(f);
        const unsigned short lb = f2bf_rne(f - bf2f(hb));
        const size_t o = (size_t)(which * 64 + hh) * 1024 + e0 + ew;
        wt_hi[o] = hb;
        wt_lo[o] = lb;
    }
}

// ---------------------------------------------------------------------------
// Kernel 1: QKV projection — R9-EXACT (best measured: 44.7 us).  DMA-staged
// W, TRIPLE-buffered (prefetch depth 2).  Block = 512 thr = 8 waves =
// (tg 0..3) x (eh 0..1); 64 tokens/block; 3 x 48KB stage = 144 KB LDS.
// (R10/R11/R12 restructures all regressed — allocator caps VGPRs ~108 and
// single-block lockstep is the structural floor; do not re-litigate.)
// ---------------------------------------------------------------------------
__global__ __launch_bounds__(512) void proj_kernel(
    const float* __restrict__ x,
    const unsigned short* __restrict__ wt_hi, const unsigned short* __restrict__ wt_lo,
    unsigned short* __restrict__ qhi, unsigned short* __restrict__ qlo,
    unsigned short* __restrict__ khi, unsigned short* __restrict__ klo,
    unsigned short* __restrict__ vt)
{
    __shared__ __align__(16) unsigned char smem[147456];  // 3 x 48KB stage; Red union
    const int tid = threadIdx.x;
    const int w = tid >> 6, lane = tid & 63;
    const int quad = lane >> 4, li = lane & 15;
    const int tg = w & 3, eh = w >> 2;
    const int row0 = (int)blockIdx.x * 64;
    const int tok = row0 + tg * 16 + li;

    f32x4 acc[12];
    #pragma unroll
    for (int mt = 0; mt < 12; mt++) acc[mt] = (f32x4){0.f, 0.f, 0.f, 0.f};

    const float* xr = x + (size_t)tok * EE + eh * 512 + quad * 8;

    // DMA lane decomposition: 8 rows x 8 chunks per 1KB group; slot s = chunk s^row
    const int r_l = lane >> 3, sl = lane & 7;
    const int cg = sl ^ r_l;
    const unsigned short* mat = (cg < 4) ? wt_hi : wt_lo;
    const int ce = (cg & 3) * 8;
    const int sA = (quad ^ (li & 7)) * 8;          // hi, swizzled read slot
    const int sB = ((4 + quad) ^ (li & 7)) * 8;    // lo

    auto dma_step = [&](int e0, unsigned char* dstbase) {
        #pragma unroll
        for (int ii = 0; ii < 6; ii++) {
            const int i = w * 6 + ii;              // 0..47
            const int ehc = i / 24;
            const int within = i % 24;
            const int row = within * 8 + r_l;      // 0..191
            const unsigned short* src = mat + (size_t)row * EE + ehc * 512 + e0 + ce;
            async_copy16(src, dstbase + ehc * 24576 + within * 1024);
        }
    };

    // prologue: two steps in flight (FIFO order: dma(0),x(0),dma(1),x(1))
    dma_step(0, smem);
    float4 fc0 = *(const float4*)(xr + 0);
    float4 fc1 = *(const float4*)(xr + 4);
    dma_step(32, smem + 49152);
    float4 fn0 = *(const float4*)(xr + 32);
    float4 fn1 = *(const float4*)(xr + 36);
    float4 ff0, ff1;

    for (int s = 0; s < 16; s++) {
        const int e0 = s * 32;
        if (s + 2 < 16) {
            dma_step(e0 + 64, smem + ((s + 2) % 3) * 49152);
            ff0 = *(const float4*)(xr + e0 + 64);
            ff1 = *(const float4*)(xr + e0 + 68);
            wait_vm<16>();                         // drain step-s set; keep s+1, s+2
        } else if (s + 1 < 16) {
            wait_vm<8>();                          // keep step s+1 set
        } else {
            wait_vm<0>();
        }
        __builtin_amdgcn_s_barrier();              // stage s valid block-wide

        float fv[8] = {fc0.x, fc0.y, fc0.z, fc0.w, fc1.x, fc1.y, fc1.z, fc1.w};
        bf16x8 bh, bl;
        #pragma unroll
        for (int jj = 0; jj < 8; jj++) {
            unsigned short hb = f2bf_rne(fv[jj]);
            bh[jj] = (short)hb;
            bl[jj] = (short)f2bf_rne(fv[jj] - bf2f(hb));
        }
        const unsigned short* Wbase =
            (const unsigned short*)(smem + (s % 3) * 49152 + eh * 24576);
        #pragma unroll
        for (int mt = 0; mt < 12; mt++) {
            const unsigned short* rb = Wbase + (mt * 16 + li) * 64;  // 128B rows
            bf16x8 Ah = *(const bf16x8*)(rb + sA);
            bf16x8 Al = *(const bf16x8*)(rb + sB);
            acc[mt] = MFMA16(Ah, bh, acc[mt]);
            acc[mt] = MFMA16(Ah, bl, acc[mt]);
            acc[mt] = MFMA16(Al, bh, acc[mt]);
        }
        __builtin_amdgcn_s_barrier();              // all done reading buf s%3
        fc0 = fn0; fc1 = fn1; fn0 = ff0; fn1 = ff1;
    }

    // ---- merge e-halves via Red union ([4 tg][192][17] f32 = 52 KB) ----
    float* Red = (float*)smem;
    if (eh == 1) {
        #pragma unroll
        for (int mt = 0; mt < 12; mt++)
            #pragma unroll
            for (int r = 0; r < 4; r++)
                Red[(size_t)(tg * 192 + mt * 16 + quad * 4 + r) * 17 + li] = acc[mt][r];
    }
    __syncthreads();
    if (eh == 0) {
        #pragma unroll
        for (int mt = 0; mt < 12; mt++)
            #pragma unroll
            for (int r = 0; r < 4; r++)
                acc[mt][r] += Red[(size_t)(tg * 192 + mt * 16 + quad * 4 + r) * 17 + li];
        const int bb = tok >> 12, tloc = tok & 4095;
        #pragma unroll
        for (int mt = 0; mt < 12; mt++) {
            if (mt < 8) {
                const int h = (mt & 3) * 16 + quad * 4;
                ushort4 hi4, lo4;
                unsigned short hb; float f;
                f = acc[mt][0]; hb = f2bf_rne(f); hi4.x = hb; lo4.x = f2bf_rne(f - bf2f(hb));
                f = acc[mt][1]; hb = f2bf_rne(f); hi4.y = hb; lo4.y = f2bf_rne(f - bf2f(hb));
                f = acc[mt][2]; hb = f2bf_rne(f); hi4.z = hb; lo4.z = f2bf_rne(f - bf2f(hb));
                f = acc[mt][3]; hb = f2bf_rne(f); hi4.w = hb; lo4.w = f2bf_rne(f - bf2f(hb));
                const size_t o = (size_t)tok * 64 + h;
                if (mt < 4) { *(ushort4*)(qhi + o) = hi4; *(ushort4*)(qlo + o) = lo4; }
                else        { *(ushort4*)(khi + o) = hi4; *(ushort4*)(klo + o) = lo4; }
            } else {
                const int hv = (mt - 8) * 16 + quad * 4;
                #pragma unroll
                for (int r = 0; r < 4; r++)
                    vt[((size_t)(bb * 64 + hv + r) << 12) + tloc] = f2bf_rne(acc[mt][r]);
            }
        }
    }
}

// ---------------------------------------------------------------------------
// Kernel 2: flash attention — R9 compute, XCD-PINNED batches: 1-D grid of
// 256 blocks; b = (lb&7)>>1, bx = ((lb>>3)<<1)|(lb&1).  With round-robin
// block->XCD dispatch, batch b's 64 blocks land on XCDs {2b, 2b+1}, whose
// 4 MiB L2 then holds that batch's entire K+V (3 MB) -> K-DMA/V loads turn
// L2-resident instead of thrashing L3 (12 MB over 8 XCDs before).  Pure
// permutation: correctness and makespan balance unchanged.
// ---------------------------------------------------------------------------
__global__ __launch_bounds__(512) void flash_kernel(
    const unsigned short* __restrict__ qhi, const unsigned short* __restrict__ qlo,
    const unsigned short* __restrict__ khi, const unsigned short* __restrict__ klo,
    const unsigned short* __restrict__ vt, float* __restrict__ out)
{
    __shared__ __align__(16) unsigned char smem[151552];
    const int tid = threadIdx.x;
    const int w = tid >> 6, lane = tid & 63;
    const int quad = lane >> 4, li = lane & 15;
    const int lb = (int)blockIdx.x;                // 0..255
    const int b  = (lb & 7) >> 1;                  // batch pinned to XCD pair
    const int bx = ((lb >> 3) << 1) | (lb & 1);    // 0..63: pair (bx, 127-bx)
    const float SM = 20.0f;                        // static softmax offset

    const unsigned short* kb_hi = khi + ((size_t)b << 18);
    const unsigned short* kb_lo = klo + ((size_t)b << 18);
    const unsigned short* vtb   = vt  + ((size_t)b << 18) + (size_t)li * 4096 + quad * 8;

    unsigned char* kbase = smem + w * 16384;       // wave-private 2x8KB
    unsigned short* PsA = (unsigned short*)(smem + 131072 + w * 2560);
    unsigned short* PsB = PsA + 640;
    float* Op = (float*)smem;                      // [8][64][33] (phase epilogue)
    float* Ml = (float*)(smem + 67584);            // [8][32]

    const int r_l4 = lane >> 4, s16 = lane & 15;
    const int slh0 = ((quad)      ^ li) * 8;       // K hi, h 0..31
    const int slh1 = ((4 + quad)  ^ li) * 8;       // K hi, h 32..63
    const int sll0 = ((8 + quad)  ^ li) * 8;       // K lo, h 0..31
    const int sll1 = ((12 + quad) ^ li) * 8;       // K lo, h 32..63

    auto dma_tile = [&](int k0, unsigned char* dst) {
        #pragma unroll
        for (int i = 0; i < 8; i++) {
            const int row = i * 4 + r_l4;          // 0..31
            const int c = s16 ^ (row & 15);
            const unsigned short* src = (c < 8)
                ? kb_hi + (size_t)(k0 + row) * 64 + c * 8
                : kb_lo + (size_t)(k0 + row) * 64 + (c - 8) * 8;
            async_copy16(src, dst + i * 1024);
        }
    };

    #pragma unroll 1
    for (int phase = 0; phase < 2; phase++) {
        const int g = phase ? (127 - bx) : bx;
        const int q0 = g * 32;
        const int n_kt = g + 1;                    // 32-token causal K-tiles
        const int tok0 = q0 + li, tok1 = tok0 + 16;

        const size_t qo0 = ((size_t)(b << 12) + tok0) * 64 + quad * 8;
        const size_t qo1 = qo0 + 16 * 64;
        const bf16x8 QhA0 = *(const bf16x8*)(qhi + qo0);
        const bf16x8 QhA1 = *(const bf16x8*)(qhi + qo0 + 32);
        const bf16x8 QlA0 = *(const bf16x8*)(qlo + qo0);
        const bf16x8 QlA1 = *(const bf16x8*)(qlo + qo0 + 32);
        const bf16x8 QhB0 = *(const bf16x8*)(qhi + qo1);
        const bf16x8 QhB1 = *(const bf16x8*)(qhi + qo1 + 32);
        const bf16x8 QlB0 = *(const bf16x8*)(qlo + qo1);
        const bf16x8 QlB1 = *(const bf16x8*)(qlo + qo1 + 32);

        f32x4 accA[4], accB[4];
        #pragma unroll
        for (int mt = 0; mt < 4; mt++) {
            accA[mt] = (f32x4){0.f, 0.f, 0.f, 0.f};
            accB[mt] = (f32x4){0.f, 0.f, 0.f, 0.f};
        }
        float lA = 0.f, lB = 0.f;

        bf16x8 Vc[4], Vn[4];
        int bufp = 0;
        if (w < n_kt) {                            // prologue for tile w
            dma_tile(w * 32, kbase);
            #pragma unroll
            for (int hf = 0; hf < 4; hf++)
                Vc[hf] = *(const bf16x8*)(vtb + (size_t)hf * 65536 + w * 32);
        }

        for (int kt = w; kt < n_kt; kt += 8) {
            const int k0 = kt * 32;

            if (kt + 8 < n_kt) {                   // prefetch next tile
                dma_tile((kt + 8) * 32, kbase + (bufp ^ 1) * 8192);
                #pragma unroll
                for (int hf = 0; hf < 4; hf++)
                    Vn[hf] = *(const bf16x8*)(vtb + (size_t)hf * 65536 + (kt + 8) * 32);
                wait_vm<12>();                     // drain current, keep prefetch
            } else {
                wait_vm<0>();
            }
            const unsigned short* Kw = (const unsigned short*)(kbase + bufp * 8192);

            f32x4 sA[2], sB[2];
            #pragma unroll
            for (int jf = 0; jf < 2; jf++) {
                const unsigned short* rb = Kw + (jf * 16 + li) * 128;  // 256B rows
                bf16x8 Kh0 = *(const bf16x8*)(rb + slh0);
                bf16x8 Kh1 = *(const bf16x8*)(rb + slh1);
                bf16x8 Kl0 = *(const bf16x8*)(rb + sll0);
                bf16x8 Kl1 = *(const bf16x8*)(rb + sll1);
                f32x4 a = (f32x4){0.f, 0.f, 0.f, 0.f};
                a = MFMA16(Kh0, QhA0, a);
                a = MFMA16(Kh1, QhA1, a);
                a = MFMA16(Kh0, QlA0, a);
                a = MFMA16(Kh1, QlA1, a);
                a = MFMA16(Kl0, QhA0, a);
                a = MFMA16(Kl1, QhA1, a);
                sA[jf] = a;
                f32x4 c2 = (f32x4){0.f, 0.f, 0.f, 0.f};
                c2 = MFMA16(Kh0, QhB0, c2);
                c2 = MFMA16(Kh1, QhB1, c2);
                c2 = MFMA16(Kh0, QlB0, c2);
                c2 = MFMA16(Kh1, QlB1, c2);
                c2 = MFMA16(Kl0, QhB0, c2);
                c2 = MFMA16(Kl1, QhB1, c2);
                sB[jf] = c2;
            }

            if (kt == n_kt - 1) {                  // causal mask, diagonal tile
                #pragma unroll
                for (int jf = 0; jf < 2; jf++)
                    #pragma unroll
                    for (int r = 0; r < 4; r++) {
                        const int j = k0 + jf * 16 + quad * 4 + r;
                        if (j > tok0) sA[jf][r] = -1e30f;
                        if (j > tok1) sB[jf][r] = -1e30f;
                    }
            }

            #pragma unroll
            for (int jf = 0; jf < 2; jf++)
                #pragma unroll
                for (int r = 0; r < 4; r++) {
                    sA[jf][r] = __expf(sA[jf][r] - SM); lA += sA[jf][r];
                    sB[jf][r] = __expf(sB[jf][r] - SM); lB += sB[jf][r];
                }

            #pragma unroll
            for (int jf = 0; jf < 2; jf++) {
                ushort4 pa, pb;
                pa.x = f2bf_rne(sA[jf][0]); pa.y = f2bf_rne(sA[jf][1]);
                pa.z = f2bf_rne(sA[jf][2]); pa.w = f2bf_rne(sA[jf][3]);
                pb.x = f2bf_rne(sB[jf][0]); pb.y = f2bf_rne(sB[jf][1]);
                pb.z = f2bf_rne(sB[jf][2]); pb.w = f2bf_rne(sB[jf][3]);
                *(ushort4*)&PsA[li * 40 + jf * 16 + quad * 4] = pa;
                *(ushort4*)&PsB[li * 40 + jf * 16 + quad * 4] = pb;
            }
            const bf16x8 PA = *(const bf16x8*)&PsA[li * 40 + quad * 8];
            const bf16x8 PB = *(const bf16x8*)&PsB[li * 40 + quad * 8];

            #pragma unroll
            for (int hf = 0; hf < 4; hf++) {
                accA[hf] = MFMA16(Vc[hf], PA, accA[hf]);
                accB[hf] = MFMA16(Vc[hf], PB, accB[hf]);
            }
            #pragma unroll
            for (int hf = 0; hf < 4; hf++) Vc[hf] = Vn[hf];
            bufp ^= 1;
        }

        lA += __shfl_xor(lA, 16); lA += __shfl_xor(lA, 32);
        lB += __shfl_xor(lB, 16); lB += __shfl_xor(lB, 32);

        __syncthreads();                           // all waves done with Kbuf
        #pragma unroll
        for (int mt = 0; mt < 4; mt++)
            #pragma unroll
            for (int r = 0; r < 4; r++) {
                Op[(size_t)w * 2112 + (mt * 16 + quad * 4 + r) * 33 + li]      = accA[mt][r];
                Op[(size_t)w * 2112 + (mt * 16 + quad * 4 + r) * 33 + li + 16] = accB[mt][r];
            }
        if (quad == 0) {
            Ml[w * 32 + li]      = lA;
            Ml[w * 32 + 16 + li] = lB;
        }
        __syncthreads();

        const int i  = tid >> 4;                   // 0..31
        const int hc = (tid & 15) * 4;
        float l = 0.f;
        #pragma unroll
        for (int ww = 0; ww < 8; ww++) l += Ml[ww * 32 + i];
        const float inv = 1.0f / (l * 8.0f);       // /= sqrt(64) after softmax
        float4 o = {0.f, 0.f, 0.f, 0.f};
        #pragma unroll
        for (int ww = 0; ww < 8; ww++) {
            const float* base = Op + (size_t)ww * 2112;
            o.x += base[(hc + 0) * 33 + i];
            o.y += base[(hc + 1) * 33 + i];
            o.z += base[(hc + 2) * 33 + i];
            o.w += base[(hc + 3) * 33 + i];
        }
        o.x *= inv; o.y *= inv; o.z *= inv; o.w *= inv;
        *(float4*)(out + ((size_t)(b << 12) + q0 + i) * 64 + hc) = o;
        __syncthreads();                           // Opart free before next phase
    }
}

// ---------------------------------------------------------------------------
extern "C" void kernel_launch(void* const* d_in, const int* in_sizes, int n_in,
                              void* d_out, int out_size, void* d_ws, size_t ws_size,
                              hipStream_t stream)
{
    const float* x  = (const float*)d_in[0];
    const float* Wq = (const float*)d_in[1];
    const float* Wk = (const float*)d_in[2];
    const float* Wv = (const float*)d_in[3];
    float* out = (float*)d_out;

    const size_t n_tok = (size_t)BB * TT * HH;    // 1,048,576
    unsigned short* qhi = (unsigned short*)d_ws;
    unsigned short* qlo = qhi + n_tok;
    unsigned short* khi = qlo + n_tok;
    unsigned short* klo = khi + n_tok;
    unsigned short* vt  = klo + n_tok;            // [B][64][4096]
    unsigned short* wt_hi = vt + n_tok;           // [192][1024]
    unsigned short* wt_lo = wt_hi + 192 * 1024;   // total ~10.75 MB

    wprep_kernel<<<48, 256, 0, stream>>>(Wq, Wk, Wv, wt_hi, wt_lo);
    proj_kernel<<<(BB * TT) / 64, 512, 0, stream>>>(x, wt_hi, wt_lo,
                                                    qhi, qlo, khi, klo, vt);
    flash_kernel<<<256, 512, 0, stream>>>(qhi, qlo, khi, klo, vt, out);
}

// Round 14
// 157.098 us; speedup vs baseline: 1.3242x; 1.0326x over previous
//
#include <hip/hip_runtime.h>
#include <math.h>

#define BB 4
#define TT 4096
#define EE 1024
#define HH 64

typedef __attribute__((ext_vector_type(8))) short bf16x8;   // 8 bf16 = 4 VGPRs
typedef _Float16 f16x8 __attribute__((ext_vector_type(8))); // 8 fp16 = 4 VGPRs
typedef __attribute__((ext_vector_type(4))) float f32x4;

#define MFMA16(a, b, c)  __builtin_amdgcn_mfma_f32_16x16x32_bf16(a, b, c, 0, 0, 0)
#define MFMA16F(a, b, c) __builtin_amdgcn_mfma_f32_16x16x32_f16(a, b, c, 0, 0, 0)

__device__ __forceinline__ unsigned short f2bf_rne(float f) {
    unsigned u = __float_as_uint(f);
    unsigned r = u + 0x7fffu + ((u >> 16) & 1u);   // round-to-nearest-even
    return (unsigned short)(r >> 16);
}
__device__ __forceinline__ float bf2f(unsigned short h) {
    return __uint_as_float(((unsigned)h) << 16);
}
__device__ __forceinline__ unsigned short f2h(float f) {
    union { _Float16 h; unsigned short u; } cv;
    cv.h = (_Float16)f;                            // v_cvt_f16_f32, RNE
    return cv.u;
}

// async 16B global->LDS DMA; LDS dest = base + lane*16 (wave-uniform base)
__device__ __forceinline__ void async_copy16(const void* g, void* l) {
    __builtin_amdgcn_global_load_lds(
        (const __attribute__((address_space(1))) void*)g,
        (__attribute__((address_space(3))) void*)l, 16, 0, 0);
}
// wait until <= N vector-memory ops outstanding (lgkm/exp untouched);
// vmcnt is a 6-bit split field: [3:0] and [15:14]
template<int N>
__device__ __forceinline__ void wait_vm() {
    __builtin_amdgcn_s_waitcnt(0x0f70 | (N & 15) | ((N >> 4) << 14));
}

// ---------------------------------------------------------------------------
// Kernel 0: W prep via LDS transpose.  wt_hi/lo[h192][e] = split-bf16 of
// W{q|k|v}[e][h].  48 blocks.  (unchanged — proj's internal compute still
// uses split-bf16 for full precision.)
// ---------------------------------------------------------------------------
__global__ __launch_bounds__(256) void wprep_kernel(
    const float* __restrict__ Wq, const float* __restrict__ Wk,
    const float* __restrict__ Wv,
    unsigned short* __restrict__ wt_hi, unsigned short* __restrict__ wt_lo)
{
    __shared__ float ts[64][65];
    const int which = blockIdx.x >> 4;
    const int e0 = (blockIdx.x & 15) * 64;
    const float* W = (which == 0) ? Wq : ((which == 1) ? Wk : Wv);
    const int t = threadIdx.x;
    const int h = t & 63;
    #pragma unroll
    for (int p = 0; p < 16; p++) {
        const int er = (t >> 6) + p * 4;
        ts[er][h] = W[(size_t)(e0 + er) * 64 + h];
    }
    __syncthreads();
    const int ew = t & 63;
    #pragma unroll
    for (int p = 0; p < 16; p++) {
        const int hh = (t >> 6) + p * 4;
        const float f = ts[ew][hh];
        const unsigned short hb = f2bf_rne(f);
        const unsigned short lb = f2bf_rne(f - bf2f(hb));
        const size_t o = (size_t)(which * 64 + hh) * 1024 + e0 + ew;
        wt_hi[o] = hb;
        wt_lo[o] = lb;
    }
}

// ---------------------------------------------------------------------------
// Kernel 1: QKV projection — R9-exact compute (best measured structure).
// Only the EPILOGUE changes: q stored as fp16 hi+lo (qhf/qlf), k stored as
// SINGLE fp16 (kf) — k's fp16 quantization (2^-12 rel) adds ~1e-3 score
// error, same order as the split-bf16 scheme; halves flash's K traffic.
// v stays bf16 transposed.
// ---------------------------------------------------------------------------
__global__ __launch_bounds__(512) void proj_kernel(
    const float* __restrict__ x,
    const unsigned short* __restrict__ wt_hi, const unsigned short* __restrict__ wt_lo,
    unsigned short* __restrict__ qhf, unsigned short* __restrict__ qlf,
    unsigned short* __restrict__ kf, unsigned short* __restrict__ vt)
{
    __shared__ __align__(16) unsigned char smem[147456];  // 3 x 48KB stage; Red union
    const int tid = threadIdx.x;
    const int w = tid >> 6, lane = tid & 63;
    const int quad = lane >> 4, li = lane & 15;
    const int tg = w & 3, eh = w >> 2;
    const int row0 = (int)blockIdx.x * 64;
    const int tok = row0 + tg * 16 + li;

    f32x4 acc[12];
    #pragma unroll
    for (int mt = 0; mt < 12; mt++) acc[mt] = (f32x4){0.f, 0.f, 0.f, 0.f};

    const float* xr = x + (size_t)tok * EE + eh * 512 + quad * 8;

    // DMA lane decomposition: 8 rows x 8 chunks per 1KB group; slot s = chunk s^row
    const int r_l = lane >> 3, sl = lane & 7;
    const int cg = sl ^ r_l;
    const unsigned short* mat = (cg < 4) ? wt_hi : wt_lo;
    const int ce = (cg & 3) * 8;
    const int sA = (quad ^ (li & 7)) * 8;          // hi, swizzled read slot
    const int sB = ((4 + quad) ^ (li & 7)) * 8;    // lo

    auto dma_step = [&](int e0, unsigned char* dstbase) {
        #pragma unroll
        for (int ii = 0; ii < 6; ii++) {
            const int i = w * 6 + ii;              // 0..47
            const int ehc = i / 24;
            const int within = i % 24;
            const int row = within * 8 + r_l;      // 0..191
            const unsigned short* src = mat + (size_t)row * EE + ehc * 512 + e0 + ce;
            async_copy16(src, dstbase + ehc * 24576 + within * 1024);
        }
    };

    // prologue: two steps in flight (FIFO order: dma(0),x(0),dma(1),x(1))
    dma_step(0, smem);
    float4 fc0 = *(const float4*)(xr + 0);
    float4 fc1 = *(const float4*)(xr + 4);
    dma_step(32, smem + 49152);
    float4 fn0 = *(const float4*)(xr + 32);
    float4 fn1 = *(const float4*)(xr + 36);
    float4 ff0, ff1;

    for (int s = 0; s < 16; s++) {
        const int e0 = s * 32;
        if (s + 2 < 16) {
            dma_step(e0 + 64, smem + ((s + 2) % 3) * 49152);
            ff0 = *(const float4*)(xr + e0 + 64);
            ff1 = *(const float4*)(xr + e0 + 68);
            wait_vm<16>();                         // drain step-s set; keep s+1, s+2
        } else if (s + 1 < 16) {
            wait_vm<8>();                          // keep step s+1 set
        } else {
            wait_vm<0>();
        }
        __builtin_amdgcn_s_barrier();              // stage s valid block-wide

        float fv[8] = {fc0.x, fc0.y, fc0.z, fc0.w, fc1.x, fc1.y, fc1.z, fc1.w};
        bf16x8 bh, bl;
        #pragma unroll
        for (int jj = 0; jj < 8; jj++) {
            unsigned short hb = f2bf_rne(fv[jj]);
            bh[jj] = (short)hb;
            bl[jj] = (short)f2bf_rne(fv[jj] - bf2f(hb));
        }
        const unsigned short* Wbase =
            (const unsigned short*)(smem + (s % 3) * 49152 + eh * 24576);
        #pragma unroll
        for (int mt = 0; mt < 12; mt++) {
            const unsigned short* rb = Wbase + (mt * 16 + li) * 64;  // 128B rows
            bf16x8 Ah = *(const bf16x8*)(rb + sA);
            bf16x8 Al = *(const bf16x8*)(rb + sB);
            acc[mt] = MFMA16(Ah, bh, acc[mt]);
            acc[mt] = MFMA16(Ah, bl, acc[mt]);
            acc[mt] = MFMA16(Al, bh, acc[mt]);
        }
        __builtin_amdgcn_s_barrier();              // all done reading buf s%3
        fc0 = fn0; fc1 = fn1; fn0 = ff0; fn1 = ff1;
    }

    // ---- merge e-halves via Red union ([4 tg][192][17] f32 = 52 KB) ----
    float* Red = (float*)smem;
    if (eh == 1) {
        #pragma unroll
        for (int mt = 0; mt < 12; mt++)
            #pragma unroll
            for (int r = 0; r < 4; r++)
                Red[(size_t)(tg * 192 + mt * 16 + quad * 4 + r) * 17 + li] = acc[mt][r];
    }
    __syncthreads();
    if (eh == 0) {
        #pragma unroll
        for (int mt = 0; mt < 12; mt++)
            #pragma unroll
            for (int r = 0; r < 4; r++)
                acc[mt][r] += Red[(size_t)(tg * 192 + mt * 16 + quad * 4 + r) * 17 + li];
        const int bb = tok >> 12, tloc = tok & 4095;
        #pragma unroll
        for (int mt = 0; mt < 12; mt++) {
            if (mt < 4) {                          // q: fp16 hi + fp16 lo
                const int h = (mt & 3) * 16 + quad * 4;
                ushort4 hi4, lo4; float f; _Float16 hh;
                union { _Float16 h; unsigned short u; } cv;
                f = acc[mt][0]; hh = (_Float16)f; cv.h = hh; hi4.x = cv.u; lo4.x = f2h(f - (float)hh);
                f = acc[mt][1]; hh = (_Float16)f; cv.h = hh; hi4.y = cv.u; lo4.y = f2h(f - (float)hh);
                f = acc[mt][2]; hh = (_Float16)f; cv.h = hh; hi4.z = cv.u; lo4.z = f2h(f - (float)hh);
                f = acc[mt][3]; hh = (_Float16)f; cv.h = hh; hi4.w = cv.u; lo4.w = f2h(f - (float)hh);
                const size_t o = (size_t)tok * 64 + h;
                *(ushort4*)(qhf + o) = hi4;
                *(ushort4*)(qlf + o) = lo4;
            } else if (mt < 8) {                   // k: SINGLE fp16
                const int h = (mt & 3) * 16 + quad * 4;
                ushort4 k4;
                k4.x = f2h(acc[mt][0]); k4.y = f2h(acc[mt][1]);
                k4.z = f2h(acc[mt][2]); k4.w = f2h(acc[mt][3]);
                *(ushort4*)(kf + (size_t)tok * 64 + h) = k4;
            } else {                               // v: bf16 transposed [h][t]
                const int hv = (mt - 8) * 16 + quad * 4;
                #pragma unroll
                for (int r = 0; r < 4; r++)
                    vt[((size_t)(bb * 64 + hv + r) << 12) + tloc] = f2bf_rne(acc[mt][r]);
            }
        }
    }
}

// ---------------------------------------------------------------------------
// Kernel 2: flash attention — R9/R13 structure with fp16-K S-phase:
// K-tile is 4 KB single-fp16 (DMA 4 instrs, was 8), S^T via
// mfma_f32_16x16x32_f16: K0·Qh0 + K1·Qh1 + K0·Ql0 + K1·Ql1 per jf per
// i-group (16 S-MFMA/iter, was 24).  P/V stay bf16 (P = e^{s-20} reaches
// e^35 — overflows fp16).  Kbuf LDS halves to 64 KB.  Uniform pair blocks
// (129 tiles each) + XCD-pinned batch decode retained.
// ---------------------------------------------------------------------------
__global__ __launch_bounds__(512) void flash_kernel(
    const unsigned short* __restrict__ qhf, const unsigned short* __restrict__ qlf,
    const unsigned short* __restrict__ kf,
    const unsigned short* __restrict__ vt, float* __restrict__ out)
{
    // [0,65536): Kbuf[8 waves][2 bufs][4096]  UNION  Op[8][64][33] f32 @0..67584
    // [67584,68608): Ml[8][32] f32;  [68608,89088): Ps[8][2][16][40] u16
    __shared__ __align__(16) unsigned char smem[89088];
    const int tid = threadIdx.x;
    const int w = tid >> 6, lane = tid & 63;
    const int quad = lane >> 4, li = lane & 15;
    const int lb = (int)blockIdx.x;                // 0..255
    const int b  = (lb & 7) >> 1;                  // batch pinned to XCD pair
    const int bx = ((lb >> 3) << 1) | (lb & 1);    // 0..63: pair (bx, 127-bx)
    const float SM = 20.0f;                        // static softmax offset

    const _Float16* kb = (const _Float16*)kf + ((size_t)b << 18);
    const unsigned short* vtb = vt + ((size_t)b << 18) + (size_t)li * 4096 + quad * 8;

    unsigned char* kbase = smem + w * 8192;        // wave-private 2x4KB
    unsigned short* PsA = (unsigned short*)(smem + 68608 + w * 2560);
    unsigned short* PsB = PsA + 640;
    float* Op = (float*)smem;                      // [8][64][33] (phase epilogue)
    float* Ml = (float*)(smem + 67584);            // [8][32]

    // DMA decomposition: 8 rows x 8 chunks per 1KB instr; slot s = chunk s^row
    const int r_l8 = lane >> 3, s8 = lane & 7;
    // frag read slots (fp16 elems within a 128B row of 8 chunks)
    const int slf0 = ((quad)     ^ (li & 7)) * 8;  // K, h 0..31
    const int slf1 = ((4 + quad) ^ (li & 7)) * 8;  // K, h 32..63

    auto dma_tile = [&](int k0, unsigned char* dst) {
        #pragma unroll
        for (int i = 0; i < 4; i++) {
            const int row = i * 8 + r_l8;          // 0..31; row&7 == r_l8
            const int c = s8 ^ r_l8;
            async_copy16(kb + (size_t)(k0 + row) * 64 + c * 8, dst + i * 1024);
        }
    };

    #pragma unroll 1
    for (int phase = 0; phase < 2; phase++) {
        const int g = phase ? (127 - bx) : bx;
        const int q0 = g * 32;
        const int n_kt = g + 1;                    // 32-token causal K-tiles
        const int tok0 = q0 + li, tok1 = tok0 + 16;

        const size_t qo0 = ((size_t)(b << 12) + tok0) * 64 + quad * 8;
        const size_t qo1 = qo0 + 16 * 64;
        const _Float16* qh_p = (const _Float16*)qhf;
        const _Float16* ql_p = (const _Float16*)qlf;
        const f16x8 QhA0 = *(const f16x8*)(qh_p + qo0);
        const f16x8 QhA1 = *(const f16x8*)(qh_p + qo0 + 32);
        const f16x8 QlA0 = *(const f16x8*)(ql_p + qo0);
        const f16x8 QlA1 = *(const f16x8*)(ql_p + qo0 + 32);
        const f16x8 QhB0 = *(const f16x8*)(qh_p + qo1);
        const f16x8 QhB1 = *(const f16x8*)(qh_p + qo1 + 32);
        const f16x8 QlB0 = *(const f16x8*)(ql_p + qo1);
        const f16x8 QlB1 = *(const f16x8*)(ql_p + qo1 + 32);

        f32x4 accA[4], accB[4];
        #pragma unroll
        for (int mt = 0; mt < 4; mt++) {
            accA[mt] = (f32x4){0.f, 0.f, 0.f, 0.f};
            accB[mt] = (f32x4){0.f, 0.f, 0.f, 0.f};
        }
        float lA = 0.f, lB = 0.f;

        bf16x8 Vc[4], Vn[4];
        int bufp = 0;
        if (w < n_kt) {                            // prologue for tile w
            dma_tile(w * 32, kbase);
            #pragma unroll
            for (int hf = 0; hf < 4; hf++)
                Vc[hf] = *(const bf16x8*)(vtb + (size_t)hf * 65536 + w * 32);
        }

        for (int kt = w; kt < n_kt; kt += 8) {
            const int k0 = kt * 32;

            if (kt + 8 < n_kt) {                   // prefetch next tile (4 DMA + 4 V)
                dma_tile((kt + 8) * 32, kbase + (bufp ^ 1) * 4096);
                #pragma unroll
                for (int hf = 0; hf < 4; hf++)
                    Vn[hf] = *(const bf16x8*)(vtb + (size_t)hf * 65536 + (kt + 8) * 32);
                wait_vm<8>();                      // drain current, keep prefetch
            } else {
                wait_vm<0>();
            }
            const _Float16* Kw = (const _Float16*)(kbase + bufp * 4096);

            // ---- S^T: 32 j-rows x 16 i-cols per i-group ----
            f32x4 sA[2], sB[2];
            #pragma unroll
            for (int jf = 0; jf < 2; jf++) {
                const _Float16* rb = Kw + (jf * 16 + li) * 64;  // 128B rows
                f16x8 K0 = *(const f16x8*)(rb + slf0);
                f16x8 K1 = *(const f16x8*)(rb + slf1);
                f32x4 a = (f32x4){0.f, 0.f, 0.f, 0.f};
                a = MFMA16F(K0, QhA0, a);
                a = MFMA16F(K1, QhA1, a);
                a = MFMA16F(K0, QlA0, a);
                a = MFMA16F(K1, QlA1, a);
                sA[jf] = a;
                f32x4 c2 = (f32x4){0.f, 0.f, 0.f, 0.f};
                c2 = MFMA16F(K0, QhB0, c2);
                c2 = MFMA16F(K1, QhB1, c2);
                c2 = MFMA16F(K0, QlB0, c2);
                c2 = MFMA16F(K1, QlB1, c2);
                sB[jf] = c2;
            }

            if (kt == n_kt - 1) {                  // causal mask, diagonal tile
                #pragma unroll
                for (int jf = 0; jf < 2; jf++)
                    #pragma unroll
                    for (int r = 0; r < 4; r++) {
                        const int j = k0 + jf * 16 + quad * 4 + r;
                        if (j > tok0) sA[jf][r] = -1e30f;
                        if (j > tok1) sB[jf][r] = -1e30f;
                    }
            }

            // ---- static-M exp + per-lane l (no cross-lane ops in loop) ----
            #pragma unroll
            for (int jf = 0; jf < 2; jf++)
                #pragma unroll
                for (int r = 0; r < 4; r++) {
                    sA[jf][r] = __expf(sA[jf][r] - SM); lA += sA[jf][r];
                    sB[jf][r] = __expf(sB[jf][r] - SM); lB += sB[jf][r];
                }

            // ---- P -> wave-private patches (bf16, B-operand layout) ----
            #pragma unroll
            for (int jf = 0; jf < 2; jf++) {
                ushort4 pa, pb;
                pa.x = f2bf_rne(sA[jf][0]); pa.y = f2bf_rne(sA[jf][1]);
                pa.z = f2bf_rne(sA[jf][2]); pa.w = f2bf_rne(sA[jf][3]);
                pb.x = f2bf_rne(sB[jf][0]); pb.y = f2bf_rne(sB[jf][1]);
                pb.z = f2bf_rne(sB[jf][2]); pb.w = f2bf_rne(sB[jf][3]);
                *(ushort4*)&PsA[li * 40 + jf * 16 + quad * 4] = pa;
                *(ushort4*)&PsB[li * 40 + jf * 16 + quad * 4] = pb;
            }
            const bf16x8 PA = *(const bf16x8*)&PsA[li * 40 + quad * 8];
            const bf16x8 PB = *(const bf16x8*)&PsB[li * 40 + quad * 8];

            // ---- O^T += Vt · P (bf16) ----
            #pragma unroll
            for (int hf = 0; hf < 4; hf++) {
                accA[hf] = MFMA16(Vc[hf], PA, accA[hf]);
                accB[hf] = MFMA16(Vc[hf], PB, accB[hf]);
            }
            #pragma unroll
            for (int hf = 0; hf < 4; hf++) Vc[hf] = Vn[hf];
            bufp ^= 1;
        }

        lA += __shfl_xor(lA, 16); lA += __shfl_xor(lA, 32);
        lB += __shfl_xor(lB, 16); lB += __shfl_xor(lB, 32);

        __syncthreads();                           // all waves done with Kbuf
        #pragma unroll
        for (int mt = 0; mt < 4; mt++)
            #pragma unroll
            for (int r = 0; r < 4; r++) {
                Op[(size_t)w * 2112 + (mt * 16 + quad * 4 + r) * 33 + li]      = accA[mt][r];
                Op[(size_t)w * 2112 + (mt * 16 + quad * 4 + r) * 33 + li + 16] = accB[mt][r];
            }
        if (quad == 0) {
            Ml[w * 32 + li]      = lA;
            Ml[w * 32 + 16 + li] = lB;
        }
        __syncthreads();

        const int i  = tid >> 4;                   // 0..31
        const int hc = (tid & 15) * 4;
        float l = 0.f;
        #pragma unroll
        for (int ww = 0; ww < 8; ww++) l += Ml[ww * 32 + i];
        const float inv = 1.0f / (l * 8.0f);       // /= sqrt(64) after softmax
        float4 o = {0.f, 0.f, 0.f, 0.f};
        #pragma unroll
        for (int ww = 0; ww < 8; ww++) {
            const float* base = Op + (size_t)ww * 2112;
            o.x += base[(hc + 0) * 33 + i];
            o.y += base[(hc + 1) * 33 + i];
            o.z += base[(hc + 2) * 33 + i];
            o.w += base[(hc + 3) * 33 + i];
        }
        o.x *= inv; o.y *= inv; o.z *= inv; o.w *= inv;
        *(float4*)(out + ((size_t)(b << 12) + q0 + i) * 64 + hc) = o;
        __syncthreads();                           // Opart free before next phase
    }
}

// ---------------------------------------------------------------------------
extern "C" void kernel_launch(void* const* d_in, const int* in_sizes, int n_in,
                              void* d_out, int out_size, void* d_ws, size_t ws_size,
                              hipStream_t stream)
{
    const float* x  = (const float*)d_in[0];
    const float* Wq = (const float*)d_in[1];
    const float* Wk = (const float*)d_in[2];
    const float* Wv = (const float*)d_in[3];
    float* out = (float*)d_out;

    const size_t n_tok = (size_t)BB * TT * HH;    // 1,048,576
    unsigned short* qhf = (unsigned short*)d_ws;  // q fp16 hi
    unsigned short* qlf = qhf + n_tok;            // q fp16 lo
    unsigned short* kf  = qlf + n_tok;            // k fp16 single
    unsigned short* vt  = kf + n_tok;             // v bf16 [B][64][4096]
    unsigned short* wt_hi = vt + n_tok;           // [192][1024]
    unsigned short* wt_lo = wt_hi + 192 * 1024;   // total ~8.8 MB

    wprep_kernel<<<48, 256, 0, stream>>>(Wq, Wk, Wv, wt_hi, wt_lo);
    proj_kernel<<<(BB * TT) / 64, 512, 0, stream>>>(x, wt_hi, wt_lo,
                                                    qhf, qlf, kf, vt);
    flash_kernel<<<256, 512, 0, stream>>>(qhf, qlf, kf, vt, out);
}